// Round 5
// baseline (4000.135 us; speedup 1.0000x reference)
//
#include <hip/hip_runtime.h>

// Neural SDE rollout, split-K x16, full occupancy (4 blocks/CU, 8 waves/SIMD).
// 64 groups x 16 rows; 16 blocks/group, each owns a 32-col H-slice
// (W1[:,slice], W2[slice,:]). Per-step partial-sum exchange via device-scope
// atomicAdd + release counter; relaxed atomic loads as coherence-point reads
// (no acquire fences -> per-XCD L2 weight caching survives). Split-fp16
// numerics (hi+lo, 3 MFMAs) -- absmax 2.0 across R2-R4.
// grid=1024 blocks @ launch_bounds(512,8): VGPR<=64, LDS~29KB -> exactly
// 4 blocks/CU resident => spin-sync is deadlock-free at full chip.

typedef _Float16 f16x8 __attribute__((ext_vector_type(8)));
typedef float    f32x4 __attribute__((ext_vector_type(4)));

#define MFMA(a,b,c) __builtin_amdgcn_mfma_f32_16x16x32_f16(a,b,c,0,0,0)

#define Bb 1024
#define Tt 128
#define NG 64          // groups
#define GB 16          // blocks per group (split-K over H=512 -> 32 cols each)
#define Rr 16          // rows per group (one MFMA M-tile)
#define NT 512         // threads per block (8 waves)

// packed fragment regions in d_ws (units: halves) -- identical pack to R3/R4
#define W2SG_OFF 0
#define W2SG_HALVES (64*16*2*512)
#define W2MU_OFF (W2SG_OFF + W2SG_HALVES)
#define W2MU_HALVES (4*16*2*512)
#define W1MU_OFF (W2MU_OFF + W2MU_HALVES)
#define W1_HALVES (32*3*2*512)
#define W1SG_OFF (W1MU_OFF + W1_HALVES)
#define WS_HALVES (W1SG_OFF + W1_HALVES)
#define ACC_BYTES_OFF ((size_t)WS_HALVES * 2)
#define ACC_FLOATS (3 * NG * 1024)        // 3 slots x 64 groups x 16x64
#define CNT_BYTES_OFF (ACC_BYTES_OFF + (size_t)ACC_FLOATS * 4)
#define CNT_STRIDE 16                     // pad counters to 64 B

__global__ __launch_bounds__(256) void pack_weights(
    const float* __restrict__ W1_mu, const float* __restrict__ W2_mu,
    const float* __restrict__ W1_sg, const float* __restrict__ W2_sg,
    _Float16* __restrict__ wsh)
{
    int gid = blockIdx.x * 256 + threadIdx.x;
    if (gid >= 81920) return;
    const float* src; int ncols, kvalid; size_t dst;
    int id, tile, ks, lane;
    if (gid < 65536) {                 // W2_sg: 64 tiles x 16 ks x 64 lanes
        id = gid; tile = id >> 10; id &= 1023; ks = id >> 6; lane = id & 63;
        src = W2_sg; ncols = 1024; kvalid = 512;
        dst = W2SG_OFF + (size_t)((tile*16 + ks)*2) * 512 + lane*8;
    } else if (gid < 69632) {          // W2_mu: 4 x 16 x 64
        id = gid - 65536; tile = id >> 10; id &= 1023; ks = id >> 6; lane = id & 63;
        src = W2_mu; ncols = 64; kvalid = 512;
        dst = W2MU_OFF + (size_t)((tile*16 + ks)*2) * 512 + lane*8;
    } else if (gid < 75776) {          // W1_mu: 32 tiles x 3 ks x 64
        id = gid - 69632; tile = id / 192; id %= 192; ks = id >> 6; lane = id & 63;
        src = W1_mu; ncols = 512; kvalid = 80;
        dst = W1MU_OFF + (size_t)((tile*3 + ks)*2) * 512 + lane*8;
    } else {                           // W1_sg
        id = gid - 75776; tile = id / 192; id %= 192; ks = id >> 6; lane = id & 63;
        src = W1_sg; ncols = 512; kvalid = 80;
        dst = W1SG_OFF + (size_t)((tile*3 + ks)*2) * 512 + lane*8;
    }
    const int n  = tile*16 + (lane & 15);
    const int kb = ks*32 + ((lane >> 4) << 3);
    f16x8 hi8, lo8;
    #pragma unroll
    for (int jj = 0; jj < 8; ++jj) {
        int k = kb + jj;
        float wv = (k < kvalid) ? src[(size_t)k * ncols + n] : 0.f;
        _Float16 h = (_Float16)wv;
        hi8[jj] = h;
        lo8[jj] = (_Float16)(wv - (float)h);
    }
    *((f16x8*)(wsh + dst))       = hi8;
    *((f16x8*)(wsh + dst + 512)) = lo8;
}

__global__ __launch_bounds__(NT, 8) void nsde_splitk(
    const float* __restrict__ y0, const float* __restrict__ controls,
    const float* __restrict__ noise,
    const float* __restrict__ b1_mu, const float* __restrict__ b2_mu,
    const float* __restrict__ b1_sg, const float* __restrict__ b2_sg,
    const _Float16* __restrict__ wf,
    float* __restrict__ accbuf, unsigned int* __restrict__ cnt,
    float* __restrict__ out)
{
    __shared__ _Float16 s_xhi[Rr][104], s_xlo[Rr][104];     // x, K=96 (+pad)
    __shared__ _Float16 s_hhi[2][Rr][36], s_hlo[2][Rr][36]; // 32-col h slices
    __shared__ float s_y[Rr*64];
    __shared__ float s_dw[Rr][16];
    __shared__ float s_part[Rr*64];  // sg partial (dW-folded)
    __shared__ float s_pmu[Rr*64];   // mu partial (*dt)
    __shared__ float s_b2sg[1024];   // b2_sg staged (zeros unless j==0)

    const int tid  = threadIdx.x;
    const int lane = tid & 63, w = tid >> 6;
    const int m15  = lane & 15, quad = lane >> 4;
    const int j    = blockIdx.x & 15;       // K-slice id (j%8 -> XCD)
    const int g    = blockIdx.x >> 4;       // group
    const int r0   = g * Rr;

    // per-wave constants (GEMM1 lives on waves 0..3)
    const int l  = w >> 1;                  // layer: 0=mu 1=sg
    const int ct = w & 1;                   // col-tile within 32-col slice
    const int tg = j*2 + ct;                // global W1 H-tile
    const _Float16* w1base = wf + (l ? W1SG_OFF : W1MU_OFF);
    const float bias1 = (w < 4) ? (l ? b1_sg : b1_mu)[j*32 + ct*16 + m15] : 0.f;
    const float b2m = (w < 4 && j == 0) ? b2_mu[w*16 + m15] * 0.01f : 0.f;
    const int ntile = (w < 4) ? 6 : 10;          // sg n-tiles per wave (24+40=64)
    const int nbase = (w < 4) ? w*6 : 24 + (w-4)*10;

    // ---- init
    for (int e = tid; e < Rr*24; e += NT) {   // zero x K-pad cols 80..103
        int r = e / 24, c = 80 + e % 24;
        s_xhi[r][c] = (_Float16)0.f; s_xlo[r][c] = (_Float16)0.f;
    }
    for (int e = tid; e < 1024; e += NT)
        s_b2sg[e] = (j == 0) ? b2_sg[e] : 0.f;
    if (tid < 256) {
        int e0 = tid*4, r = e0 >> 6, n = e0 & 63;
        float4 yv = *(const float4*)&y0[(size_t)(r0 + r)*64 + n];
        float vv[4] = {yv.x, yv.y, yv.z, yv.w};
        #pragma unroll
        for (int q = 0; q < 4; ++q) {
            s_y[e0+q] = vv[q];
            _Float16 h = (_Float16)vv[q];
            s_xhi[r][n+q] = h; s_xlo[r][n+q] = (_Float16)(vv[q] - (float)h);
        }
        if ((tid >> 4) == j)
            *(float4*)&out[(size_t)(r0 + r)*64 + n] = yv;
        int rr2 = tid >> 4, cc2 = tid & 15;
        float u = controls[cc2];
        _Float16 h = (_Float16)u;
        s_xhi[rr2][64+cc2] = h; s_xlo[rr2][64+cc2] = (_Float16)(u - (float)h);
        s_dw[rr2][cc2] = noise[(size_t)(r0 + rr2)*16 + cc2] * 0.1f;
    }
    __syncthreads();

    for (int k = 0; k < Tt-1; ++k) {
        // ======== GEMM1 (waves 0..3): h[l][:, 16-col tile] = relu(x@W1+b1)
        if (w < 4) {
            f32x4 a0 = {0,0,0,0}, a1 = {0,0,0,0}, a2 = {0,0,0,0};
            #pragma unroll
            for (int ks = 0; ks < 3; ++ks) {
                const _Float16* bp = w1base + (size_t)((tg*3 + ks)*2)*512 + lane*8;
                f16x8 bh = *(const f16x8*)bp;
                f16x8 bl = *(const f16x8*)(bp + 512);
                f16x8 ah = *(const f16x8*)&s_xhi[m15][ks*32 + quad*8];
                f16x8 al = *(const f16x8*)&s_xlo[m15][ks*32 + quad*8];
                a0 = MFMA(ah, bh, a0);
                a1 = MFMA(ah, bl, a1);
                a2 = MFMA(al, bh, a2);
            }
            f32x4 s = a0 + a1 + a2;
            #pragma unroll
            for (int rg = 0; rg < 4; ++rg) {
                int row = quad*4 + rg;
                float v = fmaxf(s[rg] + bias1, 0.f);
                _Float16 h = (_Float16)v;
                s_hhi[l][row][ct*16 + m15] = h;
                s_hlo[l][row][ct*16 + m15] = (_Float16)(v - (float)h);
            }
        }
        __syncthreads();

        // ======== GEMM2 over this block's 32-col K-slice (1 MFMA K-step)
        float dwv[4];
        #pragma unroll
        for (int rg = 0; rg < 4; ++rg)
            dwv[rg] = s_dw[quad*4 + rg][m15];

        // -- mu partial (waves 0..3, n-tile = w)
        if (w < 4) {
            f16x8 Mh0 = *(const f16x8*)&s_hhi[0][m15][quad*8];
            f16x8 Ml0 = *(const f16x8*)&s_hlo[0][m15][quad*8];
            const _Float16* bp = wf + W2MU_OFF + (size_t)((w*16 + j)*2)*512 + lane*8;
            f16x8 bh0 = *(const f16x8*)(bp);
            f16x8 bl0 = *(const f16x8*)(bp + 512);
            f32x4 hh = {0,0,0,0}, hl = {0,0,0,0}, lh = {0,0,0,0};
            hh = MFMA(Mh0, bh0, hh); hl = MFMA(Mh0, bl0, hl); lh = MFMA(Ml0, bh0, lh);
            f32x4 s = hh + hl + lh;
            #pragma unroll
            for (int rg = 0; rg < 4; ++rg)
                s_pmu[(quad*4 + rg)*64 + w*16 + m15] = s[rg]*0.01f + b2m;
        }

        // -- sg partials: ntile n-tiles per wave (waves 0-3: 6, 4-7: 10)
        f16x8 Ah0 = *(const f16x8*)&s_hhi[1][m15][quad*8];
        f16x8 Al0 = *(const f16x8*)&s_hlo[1][m15][quad*8];
        #pragma unroll 2
        for (int t = 0; t < ntile; ++t) {
            const int nt = nbase + t;
            const _Float16* bp = wf + W2SG_OFF + (size_t)((nt*16 + j)*2)*512 + lane*8;
            f16x8 bh0 = *(const f16x8*)(bp);
            f16x8 bl0 = *(const f16x8*)(bp + 512);
            f32x4 hh = {0,0,0,0}, hl = {0,0,0,0}, lh = {0,0,0,0};
            hh = MFMA(Ah0, bh0, hh); hl = MFMA(Ah0, bl0, hl); lh = MFMA(Al0, bh0, lh);
            f32x4 s = hh + hl + lh;
            const float b2v = s_b2sg[nt*16 + m15];
            #pragma unroll
            for (int rg = 0; rg < 4; ++rg) {
                float v = (s[rg] + b2v) * dwv[rg];
                v += __shfl_xor(v, 1); v += __shfl_xor(v, 2);
                v += __shfl_xor(v, 4); v += __shfl_xor(v, 8);
                if (m15 == 0) s_part[(quad*4 + rg)*64 + nt] = v;
            }
        }
        __syncthreads();

        // ======== exchange: atomicAdd partials into slot k%3
        const int slot = k % 3;
        float* ab = accbuf + ((size_t)slot*NG + g)*1024;
        const int e0 = tid*2;
        {
            float v0 = s_part[e0]   + s_pmu[e0];
            float v1 = s_part[e0+1] + s_pmu[e0+1];
            __hip_atomic_fetch_add(&ab[e0],   v0, __ATOMIC_RELAXED,
                                   __HIP_MEMORY_SCOPE_AGENT);
            __hip_atomic_fetch_add(&ab[e0+1], v1, __ATOMIC_RELAXED,
                                   __HIP_MEMORY_SCOPE_AGENT);
        }
        __syncthreads();   // drains vmcnt: all adds complete
        if (tid == 0) {
            __hip_atomic_fetch_add(&cnt[g*CNT_STRIDE], 1u, __ATOMIC_RELEASE,
                                   __HIP_MEMORY_SCOPE_AGENT);
            while (__hip_atomic_load(&cnt[g*CNT_STRIDE], __ATOMIC_RELAXED,
                                     __HIP_MEMORY_SCOPE_AGENT) < (unsigned)GB*(k+1))
                __builtin_amdgcn_s_sleep(2);
        }
        __syncthreads();

        // ======== read sum, y update, out write, next x/dW build
        {
            const int r = e0 >> 6, n = e0 & 63;
            float sum0 = __hip_atomic_load(&ab[e0], __ATOMIC_RELAXED,
                                           __HIP_MEMORY_SCOPE_AGENT);
            float sum1 = __hip_atomic_load(&ab[e0+1], __ATOMIC_RELAXED,
                                           __HIP_MEMORY_SCOPE_AGENT);
            float ya = s_y[e0]   + sum0;
            float yb = s_y[e0+1] + sum1;
            s_y[e0] = ya; s_y[e0+1] = yb;
            _Float16 ha = (_Float16)ya, hb = (_Float16)yb;
            s_xhi[r][n] = ha;   s_xlo[r][n]   = (_Float16)(ya - (float)ha);
            s_xhi[r][n+1] = hb; s_xlo[r][n+1] = (_Float16)(yb - (float)hb);
            if ((tid >> 5) == j) {   // 32-thread chunk per block: 1/16 of group
                float2 o = {ya, yb};
                *(float2*)&out[((size_t)(k+1)*Bb + r0 + r)*64 + n] = o;
                if (k >= 1) {        // zero slot (k-1)%3 (3-slot rotation safe)
                    float* zb = accbuf + ((size_t)((k-1)%3)*NG + g)*1024;
                    __hip_atomic_store(&zb[e0],   0.f, __ATOMIC_RELAXED,
                                       __HIP_MEMORY_SCOPE_AGENT);
                    __hip_atomic_store(&zb[e0+1], 0.f, __ATOMIC_RELAXED,
                                       __HIP_MEMORY_SCOPE_AGENT);
                }
            }
        }
        if (k < Tt-2 && tid < 256) {
            int r = tid >> 4, c = tid & 15;
            float u = controls[(size_t)(k+1)*16 + c];
            _Float16 h = (_Float16)u;
            s_xhi[r][64+c] = h; s_xlo[r][64+c] = (_Float16)(u - (float)h);
            s_dw[r][c] = noise[((size_t)(k+1)*Bb + r0 + r)*16 + c] * 0.1f;
        }
        __syncthreads();
    }
}

extern "C" void kernel_launch(void* const* d_in, const int* in_sizes, int n_in,
                              void* d_out, int out_size, void* d_ws, size_t ws_size,
                              hipStream_t stream) {
    const float* y0       = (const float*)d_in[0];
    const float* controls = (const float*)d_in[1];
    const float* noise    = (const float*)d_in[2];
    const float* W1_mu    = (const float*)d_in[3];
    const float* b1_mu    = (const float*)d_in[4];
    const float* W2_mu    = (const float*)d_in[5];
    const float* b2_mu    = (const float*)d_in[6];
    const float* W1_sg    = (const float*)d_in[7];
    const float* b1_sg    = (const float*)d_in[8];
    const float* W2_sg    = (const float*)d_in[9];
    const float* b2_sg    = (const float*)d_in[10];
    float* out = (float*)d_out;
    _Float16* wsh = (_Float16*)d_ws;
    float* accbuf = (float*)((char*)d_ws + ACC_BYTES_OFF);
    unsigned int* cnt = (unsigned int*)((char*)d_ws + CNT_BYTES_OFF);

    // zero accumulator slots + padded counters (ws is poisoned 0xAA each call)
    hipMemsetAsync((char*)d_ws + ACC_BYTES_OFF, 0,
                   (size_t)ACC_FLOATS*4 + (size_t)NG*CNT_STRIDE*4, stream);
    pack_weights<<<320, 256, 0, stream>>>(W1_mu, W2_mu, W1_sg, W2_sg, wsh);
    nsde_splitk<<<NG*GB, NT, 0, stream>>>(y0, controls, noise,
                                          b1_mu, b2_mu, b1_sg, b2_sg,
                                          (const _Float16*)wsh,
                                          accbuf, cnt, out);
}

// Round 6
// 3306.941 us; speedup vs baseline: 1.2096x; 1.2096x over previous
//
#include <hip/hip_runtime.h>

// Neural SDE rollout -- all-gather structure (NO atomic-RMW reduce).
// R3-R5 showed a MALL atomic throughput wall: 524K atomicAdd/step pinned
// every config at 18-31 us/step. This version gives each block a DISJOINT
// output slice (split-N over W2_sg's n-major columns; drift pair-split over K
// into two separate buffers) so the exchange is plain device-scope stores +
// one release counter per block (512 RMW/step total), then gather-loads.
// GEMM1 is replicated per block (full h) -- cheap (~72 MFMA/wave, L2-hot).
// 64 groups x 16 rows x 8 blocks = 512 blocks, NT=512, LDS ~60KB -> 2/CU.
// Split-fp16 numerics (hi+lo, 3 MFMAs) -- absmax 2.0 across R2-R5.

typedef _Float16 f16x8 __attribute__((ext_vector_type(8)));
typedef float    f32x4 __attribute__((ext_vector_type(4)));

#define MFMA(a,b,c) __builtin_amdgcn_mfma_f32_16x16x32_f16(a,b,c,0,0,0)

#define Bb 1024
#define Tt 128
#define NG 64          // groups (16 batch rows each)
#define GB 8           // blocks per group
#define Rr 16          // rows per group (one MFMA M-tile)
#define NT 512         // threads per block (8 waves)

// packed fragment regions in d_ws (units: halves) -- identical pack since R2
#define W2SG_OFF 0
#define W2SG_HALVES (64*16*2*512)
#define W2MU_OFF (W2SG_OFF + W2SG_HALVES)
#define W2MU_HALVES (4*16*2*512)
#define W1MU_OFF (W2MU_OFF + W2MU_HALVES)
#define W1_HALVES (32*3*2*512)
#define W1SG_OFF (W1MU_OFF + W1_HALVES)
#define WS_HALVES (W1SG_OFF + W1_HALVES)

// gather buffers (bytes), each: 2 slots x NG x 1024 floats
#define PSG_OFF  ((size_t)WS_HALVES * 2)
#define PMUA_OFF (PSG_OFF  + (size_t)2*NG*1024*4)
#define PMUB_OFF (PMUA_OFF + (size_t)2*NG*1024*4)
#define CNT_OFF  (PMUB_OFF + (size_t)2*NG*1024*4)
#define CNT_STRIDE 16                 // pad counters to 64 B

__global__ __launch_bounds__(256) void pack_weights(
    const float* __restrict__ W1_mu, const float* __restrict__ W2_mu,
    const float* __restrict__ W1_sg, const float* __restrict__ W2_sg,
    _Float16* __restrict__ wsh)
{
    int gid = blockIdx.x * 256 + threadIdx.x;
    if (gid >= 81920) return;
    const float* src; int ncols, kvalid; size_t dst;
    int id, tile, ks, lane;
    if (gid < 65536) {                 // W2_sg: 64 tiles x 16 ks x 64 lanes
        id = gid; tile = id >> 10; id &= 1023; ks = id >> 6; lane = id & 63;
        src = W2_sg; ncols = 1024; kvalid = 512;
        dst = W2SG_OFF + (size_t)((tile*16 + ks)*2) * 512 + lane*8;
    } else if (gid < 69632) {          // W2_mu: 4 x 16 x 64
        id = gid - 65536; tile = id >> 10; id &= 1023; ks = id >> 6; lane = id & 63;
        src = W2_mu; ncols = 64; kvalid = 512;
        dst = W2MU_OFF + (size_t)((tile*16 + ks)*2) * 512 + lane*8;
    } else if (gid < 75776) {          // W1_mu: 32 tiles x 3 ks x 64
        id = gid - 69632; tile = id / 192; id %= 192; ks = id >> 6; lane = id & 63;
        src = W1_mu; ncols = 512; kvalid = 80;
        dst = W1MU_OFF + (size_t)((tile*3 + ks)*2) * 512 + lane*8;
    } else {                           // W1_sg
        id = gid - 75776; tile = id / 192; id %= 192; ks = id >> 6; lane = id & 63;
        src = W1_sg; ncols = 512; kvalid = 80;
        dst = W1SG_OFF + (size_t)((tile*3 + ks)*2) * 512 + lane*8;
    }
    const int n  = tile*16 + (lane & 15);
    const int kb = ks*32 + ((lane >> 4) << 3);
    f16x8 hi8, lo8;
    #pragma unroll
    for (int jj = 0; jj < 8; ++jj) {
        int k = kb + jj;
        float wv = (k < kvalid) ? src[(size_t)k * ncols + n] : 0.f;
        _Float16 h = (_Float16)wv;
        hi8[jj] = h;
        lo8[jj] = (_Float16)(wv - (float)h);
    }
    *((f16x8*)(wsh + dst))       = hi8;
    *((f16x8*)(wsh + dst + 512)) = lo8;
}

__global__ __launch_bounds__(NT, 6) void nsde_gather(
    const float* __restrict__ y0, const float* __restrict__ controls,
    const float* __restrict__ noise,
    const float* __restrict__ b1_mu, const float* __restrict__ b2_mu,
    const float* __restrict__ b1_sg, const float* __restrict__ b2_sg,
    const _Float16* __restrict__ wf,
    float* __restrict__ psg, float* __restrict__ pmua,
    float* __restrict__ pmub, unsigned int* __restrict__ cnt,
    float* __restrict__ out)
{
    __shared__ _Float16 s_xhi[Rr][104], s_xlo[Rr][104];   // x, K=96 (+pad)
    __shared__ _Float16 s_sghi[Rr][520], s_sglo[Rr][520]; // h_sg FULL 512
    __shared__ _Float16 s_muhi[Rr][264], s_mulo[Rr][264]; // h_mu half-K 256
    __shared__ float s_y[Rr*64];
    __shared__ float s_dw[Rr][16];

    const int tid  = threadIdx.x;
    const int lane = tid & 63, w = tid >> 6;
    const int m15  = lane & 15, quad = lane >> 4;
    const int j    = blockIdx.x & 7;    // slice id (round-robin -> XCD)
    const int g    = blockIdx.x >> 3;   // group
    const int r0   = g * Rr;
    const int muhh = (j >= 4);          // which mu K-half this block computes

    // hoisted biases
    float b1sgv[4], b1muv[2];
    #pragma unroll
    for (int i = 0; i < 4; ++i) b1sgv[i] = b1_sg[(w*4+i)*16 + m15];
    #pragma unroll
    for (int i = 0; i < 2; ++i) b1muv[i] = b1_mu[(w*2+i + muhh*16)*16 + m15];
    const int nsg = j*8 + w;                         // owned diffusion n
    const float b2sgv = b2_sg[nsg*16 + m15];
    const int tm = j & 3;                            // owned drift tile
    const float b2muv = (j < 4) ? b2_mu[tm*16 + m15]*0.01f : 0.f;

    // ---- init
    for (int e = tid; e < Rr*24; e += NT) {   // zero x K-pad cols 80..103
        int r = e / 24, c = 80 + e % 24;
        s_xhi[r][c] = (_Float16)0.f; s_xlo[r][c] = (_Float16)0.f;
    }
    if (tid < 256) {
        int e0 = tid*4, r = e0 >> 6, n = e0 & 63;
        float4 yv = *(const float4*)&y0[(size_t)(r0 + r)*64 + n];
        float vv[4] = {yv.x, yv.y, yv.z, yv.w};
        #pragma unroll
        for (int q = 0; q < 4; ++q) {
            s_y[e0+q] = vv[q];
            _Float16 h = (_Float16)vv[q];
            s_xhi[r][n+q] = h; s_xlo[r][n+q] = (_Float16)(vv[q] - (float)h);
        }
        if ((tid >> 5) == j)
            *(float4*)&out[(size_t)(r0 + r)*64 + n] = yv;
        int rr2 = tid >> 4, cc2 = tid & 15;
        float u = controls[cc2];
        _Float16 h = (_Float16)u;
        s_xhi[rr2][64+cc2] = h; s_xlo[rr2][64+cc2] = (_Float16)(u - (float)h);
        s_dw[rr2][cc2] = noise[(size_t)(r0 + rr2)*16 + cc2] * 0.1f;
    }
    __syncthreads();

    for (int k = 0; k < Tt-1; ++k) {
        // ======== GEMM1 (replicated): full h_sg + this block's h_mu K-half
        f16x8 xah[3], xal[3];
        #pragma unroll
        for (int ks = 0; ks < 3; ++ks) {
            xah[ks] = *(const f16x8*)&s_xhi[m15][ks*32 + quad*8];
            xal[ks] = *(const f16x8*)&s_xlo[m15][ks*32 + quad*8];
        }
        #pragma unroll 2
        for (int i = 0; i < 4; ++i) {          // 4 sg H-tiles per wave
            const int t = w*4 + i;
            f32x4 a0 = {0,0,0,0}, a1 = {0,0,0,0}, a2 = {0,0,0,0};
            #pragma unroll
            for (int ks = 0; ks < 3; ++ks) {
                const _Float16* bp = wf + W1SG_OFF + (size_t)((t*3+ks)*2)*512 + lane*8;
                f16x8 bh = *(const f16x8*)bp;
                f16x8 bl = *(const f16x8*)(bp + 512);
                a0 = MFMA(xah[ks], bh, a0);
                a1 = MFMA(xah[ks], bl, a1);
                a2 = MFMA(xal[ks], bh, a2);
            }
            f32x4 s = a0 + a1 + a2;
            #pragma unroll
            for (int rg = 0; rg < 4; ++rg) {
                int row = quad*4 + rg;
                float v = fmaxf(s[rg] + b1sgv[i], 0.f);
                _Float16 h = (_Float16)v;
                s_sghi[row][t*16+m15] = h;
                s_sglo[row][t*16+m15] = (_Float16)(v - (float)h);
            }
        }
        #pragma unroll
        for (int i = 0; i < 2; ++i) {          // 2 mu H-tiles per wave
            const int tl = w*2 + i;            // local tile (LDS)
            const int tgm = tl + muhh*16;      // global W1_mu tile
            f32x4 a0 = {0,0,0,0}, a1 = {0,0,0,0}, a2 = {0,0,0,0};
            #pragma unroll
            for (int ks = 0; ks < 3; ++ks) {
                const _Float16* bp = wf + W1MU_OFF + (size_t)((tgm*3+ks)*2)*512 + lane*8;
                f16x8 bh = *(const f16x8*)bp;
                f16x8 bl = *(const f16x8*)(bp + 512);
                a0 = MFMA(xah[ks], bh, a0);
                a1 = MFMA(xah[ks], bl, a1);
                a2 = MFMA(xal[ks], bh, a2);
            }
            f32x4 s = a0 + a1 + a2;
            #pragma unroll
            for (int rg = 0; rg < 4; ++rg) {
                int row = quad*4 + rg;
                float v = fmaxf(s[rg] + b1muv[i], 0.f);
                _Float16 h = (_Float16)v;
                s_muhi[row][tl*16+m15] = h;
                s_mulo[row][tl*16+m15] = (_Float16)(v - (float)h);
            }
        }
        __syncthreads();

        const int slot = k & 1;
        float* psg_s  = psg  + ((size_t)slot*NG + g)*1024;
        float* pmua_s = pmua + ((size_t)slot*NG + g)*1024;
        float* pmub_s = pmub + ((size_t)slot*NG + g)*1024;

        float dwv[4];
        #pragma unroll
        for (int rg = 0; rg < 4; ++rg)
            dwv[rg] = s_dw[quad*4 + rg][m15];

        // ======== GEMM2 sg: owned n-tile (n = nsg), full K=512, fold dW
        {
            f32x4 hh = {0,0,0,0}, hl = {0,0,0,0}, lh = {0,0,0,0};
            #pragma unroll 2
            for (int ks = 0; ks < 16; ++ks) {
                const _Float16* bp = wf + W2SG_OFF + (size_t)((nsg*16+ks)*2)*512 + lane*8;
                f16x8 bh = *(const f16x8*)bp;
                f16x8 bl = *(const f16x8*)(bp + 512);
                f16x8 ah = *(const f16x8*)&s_sghi[m15][ks*32 + quad*8];
                f16x8 al = *(const f16x8*)&s_sglo[m15][ks*32 + quad*8];
                hh = MFMA(ah, bh, hh); hl = MFMA(ah, bl, hl); lh = MFMA(al, bh, lh);
            }
            f32x4 s = hh + hl + lh;
            #pragma unroll
            for (int rg = 0; rg < 4; ++rg) {
                float v = (s[rg] + b2sgv) * dwv[rg];
                v += __shfl_xor(v, 1); v += __shfl_xor(v, 2);
                v += __shfl_xor(v, 4); v += __shfl_xor(v, 8);
                if (m15 == 0)
                    __hip_atomic_store(&psg_s[(quad*4+rg)*64 + nsg], v,
                                       __ATOMIC_RELAXED, __HIP_MEMORY_SCOPE_AGENT);
            }
        }

        // ======== GEMM2 mu (wave 7): owned drift tile, this block's K-half
        if (w == 7) {
            f32x4 hh = {0,0,0,0}, hl = {0,0,0,0}, lh = {0,0,0,0};
            #pragma unroll 2
            for (int ksl = 0; ksl < 8; ++ksl) {
                const int ks = ksl + muhh*8;
                const _Float16* bp = wf + W2MU_OFF + (size_t)((tm*16+ks)*2)*512 + lane*8;
                f16x8 bh = *(const f16x8*)bp;
                f16x8 bl = *(const f16x8*)(bp + 512);
                f16x8 ah = *(const f16x8*)&s_muhi[m15][ksl*32 + quad*8];
                f16x8 al = *(const f16x8*)&s_mulo[m15][ksl*32 + quad*8];
                hh = MFMA(ah, bh, hh); hl = MFMA(ah, bl, hl); lh = MFMA(al, bh, lh);
            }
            f32x4 s = hh + hl + lh;
            float* pd = (j < 4) ? pmua_s : pmub_s;
            #pragma unroll
            for (int rg = 0; rg < 4; ++rg) {
                float v = s[rg]*0.01f + b2muv;
                __hip_atomic_store(&pd[(quad*4+rg)*64 + tm*16 + m15], v,
                                   __ATOMIC_RELAXED, __HIP_MEMORY_SCOPE_AGENT);
            }
        }
        __syncthreads();   // drains vmcnt: all stores complete

        if (tid == 0) {
            __hip_atomic_fetch_add(&cnt[g*CNT_STRIDE], 1u, __ATOMIC_RELEASE,
                                   __HIP_MEMORY_SCOPE_AGENT);
            while (__hip_atomic_load(&cnt[g*CNT_STRIDE], __ATOMIC_RELAXED,
                                     __HIP_MEMORY_SCOPE_AGENT) < (unsigned)GB*(k+1))
                __builtin_amdgcn_s_sleep(2);
        }
        __syncthreads();

        // ======== gather, y update, out write, next x/dW build
        {
            const int e0 = tid*2;
            const int r = e0 >> 6, n = e0 & 63;
            float yv[2];
            #pragma unroll
            for (int q = 0; q < 2; ++q) {
                const int e = e0 + q;
                float sum = __hip_atomic_load(&psg_s[e], __ATOMIC_RELAXED,
                                              __HIP_MEMORY_SCOPE_AGENT)
                          + __hip_atomic_load(&pmua_s[e], __ATOMIC_RELAXED,
                                              __HIP_MEMORY_SCOPE_AGENT)
                          + __hip_atomic_load(&pmub_s[e], __ATOMIC_RELAXED,
                                              __HIP_MEMORY_SCOPE_AGENT);
                float y = s_y[e] + sum;
                s_y[e] = y; yv[q] = y;
                _Float16 h = (_Float16)y;
                s_xhi[r][n+q] = h; s_xlo[r][n+q] = (_Float16)(y - (float)h);
            }
            if ((tid >> 6) == j) {   // wave j writes this block's 128-elem chunk
                float2 o = {yv[0], yv[1]};
                *(float2*)&out[((size_t)(k+1)*Bb + r0 + r)*64 + n] = o;
            }
        }
        if (k < Tt-2 && tid < 256) {
            int r = tid >> 4, c = tid & 15;
            float u = controls[(size_t)(k+1)*16 + c];
            _Float16 h = (_Float16)u;
            s_xhi[r][64+c] = h; s_xlo[r][64+c] = (_Float16)(u - (float)h);
            s_dw[r][c] = noise[((size_t)(k+1)*Bb + r0 + r)*16 + c] * 0.1f;
        }
        __syncthreads();
    }
}

extern "C" void kernel_launch(void* const* d_in, const int* in_sizes, int n_in,
                              void* d_out, int out_size, void* d_ws, size_t ws_size,
                              hipStream_t stream) {
    const float* y0       = (const float*)d_in[0];
    const float* controls = (const float*)d_in[1];
    const float* noise    = (const float*)d_in[2];
    const float* W1_mu    = (const float*)d_in[3];
    const float* b1_mu    = (const float*)d_in[4];
    const float* W2_mu    = (const float*)d_in[5];
    const float* b2_mu    = (const float*)d_in[6];
    const float* W1_sg    = (const float*)d_in[7];
    const float* b1_sg    = (const float*)d_in[8];
    const float* W2_sg    = (const float*)d_in[9];
    const float* b2_sg    = (const float*)d_in[10];
    float* out = (float*)d_out;
    _Float16* wsh = (_Float16*)d_ws;
    float* psg  = (float*)((char*)d_ws + PSG_OFF);
    float* pmua = (float*)((char*)d_ws + PMUA_OFF);
    float* pmub = (float*)((char*)d_ws + PMUB_OFF);
    unsigned int* cnt = (unsigned int*)((char*)d_ws + CNT_OFF);

    // zero only the counters (gather buffers are fully overwritten per step)
    hipMemsetAsync((char*)d_ws + CNT_OFF, 0, (size_t)NG*CNT_STRIDE*4, stream);
    pack_weights<<<320, 256, 0, stream>>>(W1_mu, W2_mu, W1_sg, W2_sg, wsh);
    nsde_gather<<<NG*GB, NT, 0, stream>>>(y0, controls, noise,
                                          b1_mu, b2_mu, b1_sg, b2_sg,
                                          (const _Float16*)wsh,
                                          psg, pmua, pmub, cnt, out);
}